// Round 3
// baseline (503.548 us; speedup 1.0000x reference)
//
#include <hip/hip_runtime.h>
#include <stdint.h>
#include <stddef.h>

#define DEVI __device__ __forceinline__

typedef __bf16 bf16;
typedef __bf16 bfx4 __attribute__((ext_vector_type(4)));
typedef __bf16 bfx8 __attribute__((ext_vector_type(8)));
typedef float  f32x4 __attribute__((ext_vector_type(4)));

#define MFMA __builtin_amdgcn_mfma_f32_16x16x32_bf16

constexpr int   Hdim   = 2048;
constexpr int   Dh     = 128;
constexpr int   Lq     = 1024;
constexpr int   Ccache = 512;
constexpr int   Stot   = 1536;   // C + L
constexpr int   QKVN   = 6144;   // D*(NQ+2*NKV)
constexpr float SCALE_LOG2E = 0.08838834764831845f * 1.4426950408889634f;
constexpr float NEGM = -30000.f; // exp2-underflow-safe "minus infinity"

DEVI uint32_t pack2(float a, float b) {
    bf16 x = (bf16)a, y = (bf16)b;
    uint16_t ux = __builtin_bit_cast(uint16_t, x), uy = __builtin_bit_cast(uint16_t, y);
    return (uint32_t)ux | ((uint32_t)uy << 16);
}
DEVI bfx8 f8_to_b8(float4 a, float4 b) {
    bfx8 r;
    r[0]=(bf16)a.x; r[1]=(bf16)a.y; r[2]=(bf16)a.z; r[3]=(bf16)a.w;
    r[4]=(bf16)b.x; r[5]=(bf16)b.y; r[6]=(bf16)b.z; r[7]=(bf16)b.w;
    return r;
}
// dual 8-element load at the same element offset
DEVI bfx8 load8d(const bf16* pb, const float* pf, int f32) {
    if (f32) return f8_to_b8(*(const float4*)pf, *(const float4*)(pf + 4));
    return *(const bfx8*)pb;
}

// ---------------------------------------------------------------------------
// dtype detect: fp32 storage => low u16 of each word is random mantissa bits
// => bf16-NaN/Inf pattern (exp=0xFF) appears ~1/256. bf16 storage => never.
// ---------------------------------------------------------------------------
__global__ __launch_bounds__(256) void k_detect(const uint32_t* __restrict__ hs,
                                                int* __restrict__ flag) {
    __shared__ int cnt;
    if (threadIdx.x == 0) cnt = 0;
    __syncthreads();
    int c = 0;
#pragma unroll
    for (int i = 0; i < 32; i++) {
        uint32_t w = hs[threadIdx.x + i * 256];
        if ((w & 0x7F80u) == 0x7F80u) c++;
    }
#pragma unroll
    for (int o = 32; o >= 1; o >>= 1) c += __shfl_xor(c, o);
    if ((threadIdx.x & 63) == 0) atomicAdd(&cnt, c);
    __syncthreads();
    if (threadIdx.x == 0) *flag = (cnt > 0) ? 1 : 0;
}

// ---------------------------------------------------------------------------
// LayerNorm (dual-dtype input), bf16 out
// ---------------------------------------------------------------------------
__global__ __launch_bounds__(256) void k_ln(const bf16* __restrict__ xb,
                                            const float* __restrict__ xf,
                                            const bf16* __restrict__ wb,
                                            const float* __restrict__ wf,
                                            const bf16* __restrict__ bbp,
                                            const float* __restrict__ bfp,
                                            bf16* __restrict__ y,
                                            const int* __restrict__ flag) {
    int f32 = *flag;
    int row = blockIdx.x;
    int tid = threadIdx.x, lane = tid & 63, wv = tid >> 6;
    float f[8];
    size_t base = (size_t)row * Hdim + tid * 8;
    if (f32) {
        float4 a = *(const float4*)(xf + base), b = *(const float4*)(xf + base + 4);
        f[0]=a.x; f[1]=a.y; f[2]=a.z; f[3]=a.w; f[4]=b.x; f[5]=b.y; f[6]=b.z; f[7]=b.w;
    } else {
        bfx8 v = *(const bfx8*)(xb + base);
#pragma unroll
        for (int i = 0; i < 8; i++) f[i] = (float)v[i];
    }
    float sum = 0.f, ss = 0.f;
#pragma unroll
    for (int i = 0; i < 8; i++) { sum += f[i]; ss += f[i] * f[i]; }
#pragma unroll
    for (int o = 32; o >= 1; o >>= 1) { sum += __shfl_xor(sum, o); ss += __shfl_xor(ss, o); }
    __shared__ float red[8];
    if (lane == 0) { red[wv] = sum; red[4 + wv] = ss; }
    __syncthreads();
    sum = red[0] + red[1] + red[2] + red[3];
    ss  = red[4] + red[5] + red[6] + red[7];
    float mu   = sum * (1.f / Hdim);
    float var  = ss * (1.f / Hdim) - mu * mu;
    float rinv = rsqrtf(var + 1e-5f);
    float wv8[8], bv8[8];
    if (f32) {
        float4 a = *(const float4*)(wf + tid * 8), b = *(const float4*)(wf + tid * 8 + 4);
        wv8[0]=a.x; wv8[1]=a.y; wv8[2]=a.z; wv8[3]=a.w; wv8[4]=b.x; wv8[5]=b.y; wv8[6]=b.z; wv8[7]=b.w;
        float4 c = *(const float4*)(bfp + tid * 8), d = *(const float4*)(bfp + tid * 8 + 4);
        bv8[0]=c.x; bv8[1]=c.y; bv8[2]=c.z; bv8[3]=c.w; bv8[4]=d.x; bv8[5]=d.y; bv8[6]=d.z; bv8[7]=d.w;
    } else {
        bfx8 w8 = ((const bfx8*)wb)[tid], b8 = ((const bfx8*)bbp)[tid];
#pragma unroll
        for (int i = 0; i < 8; i++) { wv8[i] = (float)w8[i]; bv8[i] = (float)b8[i]; }
    }
    bfx8 o;
#pragma unroll
    for (int i = 0; i < 8; i++)
        o[i] = (bf16)((f[i] - mu) * rinv * wv8[i] + bv8[i]);
    *(bfx8*)(y + base) = o;
}

// ---------------------------------------------------------------------------
// Transpose src[R][Cn] -> dst[Cn][R] (dual-dtype src, bf16 dst)
// ---------------------------------------------------------------------------
__global__ __launch_bounds__(256) void k_transpose(const bf16* __restrict__ srcb,
                                                   const float* __restrict__ srcf,
                                                   bf16* __restrict__ dst,
                                                   int R, int Cn,
                                                   const int* __restrict__ flag) {
    __shared__ uint32_t T[64][36];
    int f32 = *flag;
    int nR = R >> 6;
    int tr = blockIdx.x % nR, tc = blockIdx.x / nR;
    int r0 = tr * 64, c0 = tc * 64;
    int t = threadIdx.x, rp = t >> 3, nc = t & 7;
    size_t off0 = (size_t)(r0 + 2 * rp) * Cn + c0 + nc * 8;
    size_t off1 = (size_t)(r0 + 2 * rp + 1) * Cn + c0 + nc * 8;
    uint32_t av[4], bv[4];
    if (f32) {
        float4 a0 = *(const float4*)(srcf + off0), a1 = *(const float4*)(srcf + off0 + 4);
        float4 b0 = *(const float4*)(srcf + off1), b1 = *(const float4*)(srcf + off1 + 4);
        av[0]=pack2(a0.x,a0.y); av[1]=pack2(a0.z,a0.w); av[2]=pack2(a1.x,a1.y); av[3]=pack2(a1.z,a1.w);
        bv[0]=pack2(b0.x,b0.y); bv[1]=pack2(b0.z,b0.w); bv[2]=pack2(b1.x,b1.y); bv[3]=pack2(b1.z,b1.w);
    } else {
        uint4 a = *(const uint4*)(srcb + off0);
        uint4 b = *(const uint4*)(srcb + off1);
        av[0]=a.x; av[1]=a.y; av[2]=a.z; av[3]=a.w;
        bv[0]=b.x; bv[1]=b.y; bv[2]=b.z; bv[3]=b.w;
    }
#pragma unroll
    for (int i = 0; i < 4; i++) {
        T[nc * 8 + 2 * i    ][rp] = (av[i] & 0xffffu) | (bv[i] << 16);
        T[nc * 8 + 2 * i + 1][rp] = (av[i] >> 16) | (bv[i] & 0xffff0000u);
    }
    __syncthreads();
#pragma unroll
    for (int st = 0; st < 2; ++st) {
        int s2 = t + st * 256;
        int n = s2 & 63, c4 = s2 >> 6;
        uint4 o;
        o.x = T[n][c4 * 4]; o.y = T[n][c4 * 4 + 1]; o.z = T[n][c4 * 4 + 2]; o.w = T[n][c4 * 4 + 3];
        *(uint4*)(dst + (size_t)(c0 + n) * R + r0 + c4 * 8) = o;
    }
}

// ---------------------------------------------------------------------------
// Build Vt[bh][d][s] from v_cache (dual-dtype, s<512) + qkv v-part (bf16)
// ---------------------------------------------------------------------------
__global__ __launch_bounds__(256) void k_build_vt(const bf16* __restrict__ vcb,
                                                  const float* __restrict__ vcf,
                                                  const bf16* __restrict__ qkv,
                                                  bf16* __restrict__ Vt,
                                                  const int* __restrict__ flag) {
    __shared__ uint32_t T[64][36];
    int f32 = *flag;
    int bid = blockIdx.x;
    int dt = bid & 1, st = (bid >> 1) % 24, bh = bid / 48;
    int b = bh >> 4, h = bh & 15;
    int t = threadIdx.x, rp = t >> 3, nc = t & 7;
    int s0 = st * 64 + 2 * rp;
    uint32_t av[4], bv[4];
    if (s0 < Ccache) {
        size_t off0 = ((size_t)(b * 2048 + s0) * 16 + h) * Dh + dt * 64 + nc * 8;
        size_t off1 = ((size_t)(b * 2048 + s0 + 1) * 16 + h) * Dh + dt * 64 + nc * 8;
        if (f32) {
            float4 a0 = *(const float4*)(vcf + off0), a1 = *(const float4*)(vcf + off0 + 4);
            float4 b0 = *(const float4*)(vcf + off1), b1 = *(const float4*)(vcf + off1 + 4);
            av[0]=pack2(a0.x,a0.y); av[1]=pack2(a0.z,a0.w); av[2]=pack2(a1.x,a1.y); av[3]=pack2(a1.z,a1.w);
            bv[0]=pack2(b0.x,b0.y); bv[1]=pack2(b0.z,b0.w); bv[2]=pack2(b1.x,b1.y); bv[3]=pack2(b1.z,b1.w);
        } else {
            uint4 a = *(const uint4*)(vcb + off0);
            uint4 bq = *(const uint4*)(vcb + off1);
            av[0]=a.x; av[1]=a.y; av[2]=a.z; av[3]=a.w;
            bv[0]=bq.x; bv[1]=bq.y; bv[2]=bq.z; bv[3]=bq.w;
        }
    } else {
        const bf16* r0p = qkv + (size_t)(b * Lq + s0 - Ccache) * QKVN + 4096 + h * Dh + dt * 64 + nc * 8;
        const bf16* r1p = qkv + (size_t)(b * Lq + s0 + 1 - Ccache) * QKVN + 4096 + h * Dh + dt * 64 + nc * 8;
        uint4 a = *(const uint4*)r0p;
        uint4 bq = *(const uint4*)r1p;
        av[0]=a.x; av[1]=a.y; av[2]=a.z; av[3]=a.w;
        bv[0]=bq.x; bv[1]=bq.y; bv[2]=bq.z; bv[3]=bq.w;
    }
#pragma unroll
    for (int i = 0; i < 4; i++) {
        T[nc * 8 + 2 * i    ][rp] = (av[i] & 0xffffu) | (bv[i] << 16);
        T[nc * 8 + 2 * i + 1][rp] = (av[i] >> 16) | (bv[i] & 0xffff0000u);
    }
    __syncthreads();
#pragma unroll
    for (int st2 = 0; st2 < 2; ++st2) {
        int s2 = t + st2 * 256;
        int n = s2 & 63, c4 = s2 >> 6;
        uint4 o;
        o.x = T[n][c4 * 4]; o.y = T[n][c4 * 4 + 1]; o.z = T[n][c4 * 4 + 2]; o.w = T[n][c4 * 4 + 3];
        *(uint4*)(Vt + ((size_t)bh * Dh + dt * 64 + n) * Stot + st * 64 + c4 * 8) = o;
    }
}

// ---------------------------------------------------------------------------
// GEMM: C = A[M,K] * Bt[N,K]^T + bias[N]. A,Bt bf16 (ws); bias dual; out dual.
// ---------------------------------------------------------------------------
__global__ __launch_bounds__(256) void k_gemm_bt(const bf16* __restrict__ A,
                                                 const bf16* __restrict__ Bt,
                                                 const bf16* __restrict__ biasb,
                                                 const float* __restrict__ biasf,
                                                 void* __restrict__ Cout,
                                                 int M, int N, int K,
                                                 const int* __restrict__ flag,
                                                 int want_f32_out) {
    __shared__ char smem[32768];
    int f32 = *flag;
    int f32o = want_f32_out & f32;
    int nbm = M >> 7;
    int bm = blockIdx.x % nbm, bn = blockIdx.x / nbm;
    int tid = threadIdx.x, lane = tid & 63, quad = lane >> 4, l15 = lane & 15;
    int w = tid >> 6, wm = w >> 1, wn = w & 1;
    f32x4 acc[4][4] = {};
    const bf16* Abase = A  + (size_t)(bm * 128) * K;
    const bf16* Bbase = Bt + (size_t)(bn * 128) * K;

    for (int kt = 0; kt < K; kt += 64) {
        bfx8 a4[4], b4[4];
#pragma unroll
        for (int stp = 0; stp < 4; ++stp) {
            int s = stp * 256 + tid;
            int row = s >> 3, cc = s & 7, gc = cc ^ (row & 7);
            a4[stp] = *(const bfx8*)(Abase + (size_t)row * K + kt + gc * 8);
            b4[stp] = *(const bfx8*)(Bbase + (size_t)row * K + kt + gc * 8);
        }
        __syncthreads();
#pragma unroll
        for (int stp = 0; stp < 4; ++stp) {
            int s = stp * 256 + tid;
            *(bfx8*)(smem + s * 16) = a4[stp];
            *(bfx8*)(smem + 16384 + s * 16) = b4[stp];
        }
        __syncthreads();
#pragma unroll
        for (int kk = 0; kk < 2; ++kk) {
            bfx8 af[4], bfr[4];
#pragma unroll
            for (int i = 0; i < 4; i++) {
                int row = wm * 64 + i * 16 + l15;
                int ch = (kk * 4 + quad) ^ (row & 7);
                af[i] = *(const bfx8*)(smem + row * 128 + ch * 16);
            }
#pragma unroll
            for (int j = 0; j < 4; j++) {
                int row = wn * 64 + j * 16 + l15;
                int ch = (kk * 4 + quad) ^ (row & 7);
                bfr[j] = *(const bfx8*)(smem + 16384 + row * 128 + ch * 16);
            }
#pragma unroll
            for (int i = 0; i < 4; i++)
#pragma unroll
                for (int j = 0; j < 4; j++)
                    acc[i][j] = MFMA(af[i], bfr[j], acc[i][j], 0, 0, 0);
        }
        __syncthreads();
    }
    float bsv[4];
#pragma unroll
    for (int j = 0; j < 4; j++) {
        int idx = bn * 128 + wn * 64 + j * 16 + l15;
        bsv[j] = f32 ? biasf[idx] : (float)biasb[idx];
    }
    bf16*  Cb = (bf16*)Cout;
    float* Cf = (float*)Cout;
#pragma unroll
    for (int i = 0; i < 4; i++) {
        int mrow = bm * 128 + wm * 64 + i * 16 + quad * 4;
#pragma unroll
        for (int j = 0; j < 4; j++) {
            int ncol = bn * 128 + wn * 64 + j * 16 + l15;
#pragma unroll
            for (int r = 0; r < 4; r++) {
                float val = acc[i][j][r] + bsv[j];
                if (f32o) Cf[(size_t)(mrow + r) * N + ncol] = val;
                else      Cb[(size_t)(mrow + r) * N + ncol] = (bf16)val;
            }
        }
    }
}

// ---------------------------------------------------------------------------
// Flash attention: S^T = K*Q^T ; O^T = V^T * P^T. k_cache dual-dtype.
// ---------------------------------------------------------------------------
__global__ __launch_bounds__(256) void k_attn(const bf16* __restrict__ qkv,
                                              const bf16* __restrict__ kcb,
                                              const float* __restrict__ kcf,
                                              const bf16* __restrict__ Vt,
                                              bf16* __restrict__ aout,
                                              const int* __restrict__ flag) {
    __shared__ char smem[51200];
    int f32 = *flag;
    int bid = blockIdx.x;
    int bh = bid & 63;
    int qi = 7 - (bid >> 6);
    int b = bh >> 4, h = bh & 15;
    int q0 = qi * 128;
    int tid = threadIdx.x, lane = tid & 63, w = tid >> 6, quad = lane >> 4, l15 = lane & 15;

#pragma unroll
    for (int stp = 0; stp < 8; ++stp) {
        int s = stp * 256 + tid;
        int row = s >> 4, cc = s & 15, gc = cc ^ (row & 7);
        bfx8 t = *(const bfx8*)(qkv + (size_t)(b * Lq + q0 + row) * QKVN + h * Dh + gc * 8);
        *(bfx8*)(smem + s * 16) = t;
    }
    __syncthreads();
    bfx8 qf[2][4];
#pragma unroll
    for (int qn = 0; qn < 2; qn++)
#pragma unroll
        for (int c = 0; c < 4; c++) {
            int row = w * 32 + qn * 16 + l15;
            int ch = (c * 4 + quad) ^ (row & 7);
            qf[qn][c] = *(const bfx8*)(smem + row * 256 + ch * 16);
        }
    __syncthreads();

    f32x4 oacc[8][2] = {};
    float mrun[2] = {NEGM, NEGM};
    float lrun[2] = {0.f, 0.f};
    char* Ks = smem;
    char* Vs = smem + 16384;
    char* Pw = smem + 32768 + w * 4608;

    int nkt = (Ccache + q0 + 128) >> 6;
    for (int kt = 0; kt < nkt; ++kt) {
        int kbase = kt * 64;
        bfx8 kreg[4], vreg[4];
#pragma unroll
        for (int stp = 0; stp < 4; ++stp) {
            int s = stp * 256 + tid;
            int row = s >> 4, cc = s & 15, gc = cc ^ (row & 7);
            int kp = kbase + row;
            if (kp < Ccache) {
                size_t off = ((size_t)(b * 2048 + kp) * 16 + h) * Dh + gc * 8;
                kreg[stp] = f32 ? f8_to_b8(*(const float4*)(kcf + off), *(const float4*)(kcf + off + 4))
                                : *(const bfx8*)(kcb + off);
            } else {
                kreg[stp] = *(const bfx8*)(qkv + (size_t)(b * Lq + kp - Ccache) * QKVN + 2048 + h * Dh + gc * 8);
            }
        }
#pragma unroll
        for (int stp = 0; stp < 4; ++stp) {
            int s = stp * 256 + tid;
            int row = s >> 3, cc = s & 7, gc = cc ^ (row & 7);
            vreg[stp] = *(const bfx8*)(Vt + ((size_t)bh * Dh + row) * Stot + kbase + gc * 8);
        }
#pragma unroll
        for (int stp = 0; stp < 4; ++stp) {
            int sk = stp * 256 + tid;
            *(bfx8*)(Ks + sk * 16) = kreg[stp];
            *(bfx8*)(Vs + sk * 16) = vreg[stp];
        }
        __syncthreads();

        f32x4 sc[4][2] = {};
#pragma unroll
        for (int c = 0; c < 4; c++) {
            bfx8 kf[4];
#pragma unroll
            for (int km = 0; km < 4; km++) {
                int row = km * 16 + l15;
                int ch = (c * 4 + quad) ^ (row & 7);
                kf[km] = *(const bfx8*)(Ks + row * 256 + ch * 16);
            }
#pragma unroll
            for (int km = 0; km < 4; km++)
#pragma unroll
                for (int qn = 0; qn < 2; qn++)
                    sc[km][qn] = MFMA(kf[km], qf[qn][c], sc[km][qn], 0, 0, 0);
        }

        bool domask = (kbase + 63) > (Ccache + q0 + w * 32);
#pragma unroll
        for (int qn = 0; qn < 2; qn++) {
            int qpos = Ccache + q0 + w * 32 + qn * 16 + l15;
            float tv[4][4];
            float tmax = NEGM;
#pragma unroll
            for (int km = 0; km < 4; km++)
#pragma unroll
                for (int r = 0; r < 4; r++) {
                    float vv = sc[km][qn][r] * SCALE_LOG2E;
                    if (domask) {
                        int kp = kbase + km * 16 + quad * 4 + r;
                        vv = (kp <= qpos) ? vv : NEGM;
                    }
                    tv[km][r] = vv;
                    tmax = fmaxf(tmax, vv);
                }
            tmax = fmaxf(tmax, __shfl_xor(tmax, 16));
            tmax = fmaxf(tmax, __shfl_xor(tmax, 32));
            float mnew  = fmaxf(mrun[qn], tmax);
            float alpha = __builtin_amdgcn_exp2f(mrun[qn] - mnew);
            mrun[qn] = mnew;
            float rs = 0.f;
#pragma unroll
            for (int km = 0; km < 4; km++) {
                float a0 = __builtin_amdgcn_exp2f(tv[km][0] - mnew);
                float a1 = __builtin_amdgcn_exp2f(tv[km][1] - mnew);
                float a2 = __builtin_amdgcn_exp2f(tv[km][2] - mnew);
                float a3 = __builtin_amdgcn_exp2f(tv[km][3] - mnew);
                rs += a0 + a1 + a2 + a3;
                bfx4 p = {(bf16)a0, (bf16)a1, (bf16)a2, (bf16)a3};
                *(bfx4*)(Pw + (qn * 16 + l15) * 144 + km * 32 + quad * 8) = p;
            }
            rs += __shfl_xor(rs, 16);
            rs += __shfl_xor(rs, 32);
            lrun[qn] = lrun[qn] * alpha + rs;
#pragma unroll
            for (int dm = 0; dm < 8; dm++)
                oacc[dm][qn] *= alpha;
        }
        __syncthreads();

#pragma unroll
        for (int kh = 0; kh < 2; kh++) {
            bfx8 pf[2];
#pragma unroll
            for (int qn = 0; qn < 2; qn++)
                pf[qn] = *(const bfx8*)(Pw + (qn * 16 + l15) * 144 + kh * 64 + quad * 16);
#pragma unroll
            for (int dm = 0; dm < 8; dm++) {
                int row = dm * 16 + l15;
                int ch = (kh * 4 + quad) ^ (row & 7);
                bfx8 vf = *(const bfx8*)(Vs + row * 128 + ch * 16);
#pragma unroll
                for (int qn = 0; qn < 2; qn++)
                    oacc[dm][qn] = MFMA(vf, pf[qn], oacc[dm][qn], 0, 0, 0);
            }
        }
        __syncthreads();
    }

#pragma unroll
    for (int qn = 0; qn < 2; qn++) {
        float rl = 1.f / lrun[qn];
        int trow = b * Lq + q0 + w * 32 + qn * 16 + l15;
#pragma unroll
        for (int dm = 0; dm < 8; dm++) {
            bfx4 o = {(bf16)(oacc[dm][qn][0] * rl), (bf16)(oacc[dm][qn][1] * rl),
                      (bf16)(oacc[dm][qn][2] * rl), (bf16)(oacc[dm][qn][3] * rl)};
            *(bfx4*)(aout + (size_t)trow * Hdim + h * Dh + dm * 16 + quad * 4) = o;
        }
    }
}

// ---------------------------------------------------------------------------
extern "C" void kernel_launch(void* const* d_in, const int* in_sizes, int n_in,
                              void* d_out, int out_size, void* d_ws, size_t ws_size,
                              hipStream_t stream) {
    char* ws = (char*)d_ws;
    // ws layout (peak 88 MiB + 4 B):
    bf16* x_ln = (bf16*)(ws);                      // [0,16M)
    bf16* Wt   = (bf16*)(ws + (16u << 20));        // [16M,40M)
    bf16* qkv  = (bf16*)(ws + (40u << 20));        // [40M,88M)
    int*  flag = (int*)(ws + (88u << 20));         // 4 B
    bf16* VtT  = (bf16*)(ws);                      // [0,24M)  after QKV GEMM
    bf16* aout = (bf16*)(ws + (24u << 20));        // [24M,40M)
    bf16* Pt   = (bf16*)(ws + (40u << 20));        // [40M,48M) after attention

    k_detect<<<dim3(1), dim3(256), 0, stream>>>((const uint32_t*)d_in[0], flag);
    k_ln<<<dim3(4096), dim3(256), 0, stream>>>(
        (const bf16*)d_in[0], (const float*)d_in[0],
        (const bf16*)d_in[6], (const float*)d_in[6],
        (const bf16*)d_in[7], (const float*)d_in[7], x_ln, flag);
    k_transpose<<<dim3(32 * 96), dim3(256), 0, stream>>>(
        (const bf16*)d_in[8], (const float*)d_in[8], Wt, 2048, 6144, flag);
    k_gemm_bt<<<dim3(32 * 48), dim3(256), 0, stream>>>(
        x_ln, Wt, (const bf16*)d_in[9], (const float*)d_in[9],
        qkv, 4096, 6144, 2048, flag, 0);
    k_build_vt<<<dim3(64 * 48), dim3(256), 0, stream>>>(
        (const bf16*)d_in[3], (const float*)d_in[3], qkv, VtT, flag);
    k_attn<<<dim3(512), dim3(256), 0, stream>>>(
        qkv, (const bf16*)d_in[2], (const float*)d_in[2], VtT, aout, flag);
    k_transpose<<<dim3(32 * 32), dim3(256), 0, stream>>>(
        (const bf16*)d_in[10], (const float*)d_in[10], Pt, 2048, 2048, flag);
    k_gemm_bt<<<dim3(16 * 32), dim3(256), 0, stream>>>(
        aout, Pt, (const bf16*)d_in[11], (const float*)d_in[11],
        d_out, 4096, 2048, 2048, flag, 1);
}

// Round 4
// 454.570 us; speedup vs baseline: 1.1077x; 1.1077x over previous
//
#include <hip/hip_runtime.h>
#include <stdint.h>
#include <stddef.h>

#define DEVI __device__ __forceinline__

typedef __bf16 bf16;
typedef __bf16 bfx4 __attribute__((ext_vector_type(4)));
typedef __bf16 bfx8 __attribute__((ext_vector_type(8)));
typedef float  f32x4 __attribute__((ext_vector_type(4)));

#define MFMA __builtin_amdgcn_mfma_f32_16x16x32_bf16

constexpr int   Hdim   = 2048;
constexpr int   Dh     = 128;
constexpr int   Lq     = 1024;
constexpr int   Ccache = 512;
constexpr int   Stot   = 1536;   // C + L
constexpr float SCALE_LOG2E = 0.08838834764831845f * 1.4426950408889634f;
constexpr float NEGM = -30000.f; // exp2-underflow-safe "minus infinity"

DEVI void gload_lds16(const void* g, void* l) {
    __builtin_amdgcn_global_load_lds((const __attribute__((address_space(1))) void*)g,
                                     (__attribute__((address_space(3))) void*)l, 16, 0, 0);
}
DEVI uint32_t pack2(float a, float b) {
    bf16 x = (bf16)a, y = (bf16)b;
    uint16_t ux = __builtin_bit_cast(uint16_t, x), uy = __builtin_bit_cast(uint16_t, y);
    return (uint32_t)ux | ((uint32_t)uy << 16);
}
DEVI bfx8 f8_to_b8(float4 a, float4 b) {
    bfx8 r;
    r[0]=(bf16)a.x; r[1]=(bf16)a.y; r[2]=(bf16)a.z; r[3]=(bf16)a.w;
    r[4]=(bf16)b.x; r[5]=(bf16)b.y; r[6]=(bf16)b.z; r[7]=(bf16)b.w;
    return r;
}

// ---------------------------------------------------------------------------
// dtype detect: fp32 storage => low u16 of a word shows bf16-NaN/Inf ~1/256
// ---------------------------------------------------------------------------
__global__ __launch_bounds__(256) void k_detect(const uint32_t* __restrict__ hs,
                                                int* __restrict__ flag) {
    __shared__ int cnt;
    if (threadIdx.x == 0) cnt = 0;
    __syncthreads();
    int c = 0;
#pragma unroll
    for (int i = 0; i < 32; i++) {
        uint32_t w = hs[threadIdx.x + i * 256];
        if ((w & 0x7F80u) == 0x7F80u) c++;
    }
#pragma unroll
    for (int o = 32; o >= 1; o >>= 1) c += __shfl_xor(c, o);
    if ((threadIdx.x & 63) == 0) atomicAdd(&cnt, c);
    __syncthreads();
    if (threadIdx.x == 0) *flag = (cnt > 0) ? 1 : 0;
}

// ---------------------------------------------------------------------------
// LayerNorm (dual-dtype input), bf16 out
// ---------------------------------------------------------------------------
__global__ __launch_bounds__(256) void k_ln(const bf16* __restrict__ xb,
                                            const float* __restrict__ xf,
                                            const bf16* __restrict__ wb,
                                            const float* __restrict__ wf,
                                            const bf16* __restrict__ bbp,
                                            const float* __restrict__ bfp,
                                            bf16* __restrict__ y,
                                            const int* __restrict__ flag) {
    int f32 = *flag;
    int row = blockIdx.x;
    int tid = threadIdx.x, lane = tid & 63, wv = tid >> 6;
    float f[8];
    size_t base = (size_t)row * Hdim + tid * 8;
    if (f32) {
        float4 a = *(const float4*)(xf + base), b = *(const float4*)(xf + base + 4);
        f[0]=a.x; f[1]=a.y; f[2]=a.z; f[3]=a.w; f[4]=b.x; f[5]=b.y; f[6]=b.z; f[7]=b.w;
    } else {
        bfx8 v = *(const bfx8*)(xb + base);
#pragma unroll
        for (int i = 0; i < 8; i++) f[i] = (float)v[i];
    }
    float sum = 0.f, ss = 0.f;
#pragma unroll
    for (int i = 0; i < 8; i++) { sum += f[i]; ss += f[i] * f[i]; }
#pragma unroll
    for (int o = 32; o >= 1; o >>= 1) { sum += __shfl_xor(sum, o); ss += __shfl_xor(ss, o); }
    __shared__ float red[8];
    if (lane == 0) { red[wv] = sum; red[4 + wv] = ss; }
    __syncthreads();
    sum = red[0] + red[1] + red[2] + red[3];
    ss  = red[4] + red[5] + red[6] + red[7];
    float mu   = sum * (1.f / Hdim);
    float var  = ss * (1.f / Hdim) - mu * mu;
    float rinv = rsqrtf(var + 1e-5f);
    float wv8[8], bv8[8];
    if (f32) {
        float4 a = *(const float4*)(wf + tid * 8), b = *(const float4*)(wf + tid * 8 + 4);
        wv8[0]=a.x; wv8[1]=a.y; wv8[2]=a.z; wv8[3]=a.w; wv8[4]=b.x; wv8[5]=b.y; wv8[6]=b.z; wv8[7]=b.w;
        float4 c = *(const float4*)(bfp + tid * 8), d = *(const float4*)(bfp + tid * 8 + 4);
        bv8[0]=c.x; bv8[1]=c.y; bv8[2]=c.z; bv8[3]=c.w; bv8[4]=d.x; bv8[5]=d.y; bv8[6]=d.z; bv8[7]=d.w;
    } else {
        bfx8 w8 = ((const bfx8*)wb)[tid], b8 = ((const bfx8*)bbp)[tid];
#pragma unroll
        for (int i = 0; i < 8; i++) { wv8[i] = (float)w8[i]; bv8[i] = (float)b8[i]; }
    }
    bfx8 o;
#pragma unroll
    for (int i = 0; i < 8; i++)
        o[i] = (bf16)((f[i] - mu) * rinv * wv8[i] + bv8[i]);
    *(bfx8*)(y + base) = o;
}

// ---------------------------------------------------------------------------
// Transpose src[R][Cn] -> dst[Cn][R] (dual-dtype src, bf16 dst)
// ---------------------------------------------------------------------------
__global__ __launch_bounds__(256) void k_transpose(const bf16* __restrict__ srcb,
                                                   const float* __restrict__ srcf,
                                                   bf16* __restrict__ dst,
                                                   int R, int Cn,
                                                   const int* __restrict__ flag) {
    __shared__ uint32_t T[64][36];
    int f32 = *flag;
    int nR = R >> 6;
    int tr = blockIdx.x % nR, tc = blockIdx.x / nR;
    int r0 = tr * 64, c0 = tc * 64;
    int t = threadIdx.x, rp = t >> 3, nc = t & 7;
    size_t off0 = (size_t)(r0 + 2 * rp) * Cn + c0 + nc * 8;
    size_t off1 = (size_t)(r0 + 2 * rp + 1) * Cn + c0 + nc * 8;
    uint32_t av[4], bv[4];
    if (f32) {
        float4 a0 = *(const float4*)(srcf + off0), a1 = *(const float4*)(srcf + off0 + 4);
        float4 b0 = *(const float4*)(srcf + off1), b1 = *(const float4*)(srcf + off1 + 4);
        av[0]=pack2(a0.x,a0.y); av[1]=pack2(a0.z,a0.w); av[2]=pack2(a1.x,a1.y); av[3]=pack2(a1.z,a1.w);
        bv[0]=pack2(b0.x,b0.y); bv[1]=pack2(b0.z,b0.w); bv[2]=pack2(b1.x,b1.y); bv[3]=pack2(b1.z,b1.w);
    } else {
        uint4 a = *(const uint4*)(srcb + off0);
        uint4 b = *(const uint4*)(srcb + off1);
        av[0]=a.x; av[1]=a.y; av[2]=a.z; av[3]=a.w;
        bv[0]=b.x; bv[1]=b.y; bv[2]=b.z; bv[3]=b.w;
    }
#pragma unroll
    for (int i = 0; i < 4; i++) {
        T[nc * 8 + 2 * i    ][rp] = (av[i] & 0xffffu) | (bv[i] << 16);
        T[nc * 8 + 2 * i + 1][rp] = (av[i] >> 16) | (bv[i] & 0xffff0000u);
    }
    __syncthreads();
#pragma unroll
    for (int st = 0; st < 2; ++st) {
        int s2 = t + st * 256;
        int n = s2 & 63, c4 = s2 >> 6;
        uint4 o;
        o.x = T[n][c4 * 4]; o.y = T[n][c4 * 4 + 1]; o.z = T[n][c4 * 4 + 2]; o.w = T[n][c4 * 4 + 3];
        *(uint4*)(dst + (size_t)(c0 + n) * R + r0 + c4 * 8) = o;
    }
}

// ---------------------------------------------------------------------------
// K-cache prefix: kcache[b][s<512][h][d] (dual) -> Kt[bh][s][d] bf16
// ---------------------------------------------------------------------------
__global__ __launch_bounds__(256) void k_cache_k(const bf16* __restrict__ kcb,
                                                 const float* __restrict__ kcf,
                                                 bf16* __restrict__ Kt,
                                                 const int* __restrict__ flag) {
    int f32 = *flag;
    size_t e = ((size_t)blockIdx.x * 256 + threadIdx.x) * 8;
    int d = e & 127, s = (e >> 7) & 511, bh = e >> 16;
    int b = bh >> 4, h = bh & 15;
    size_t src = ((size_t)(b * 2048 + s) * 16 + h) * Dh + d;
    bfx8 v = f32 ? f8_to_b8(*(const float4*)(kcf + src), *(const float4*)(kcf + src + 4))
                 : *(const bfx8*)(kcb + src);
    *(bfx8*)(Kt + ((size_t)bh * Stot + s) * Dh + d) = v;
}

// ---------------------------------------------------------------------------
// V-cache prefix: vcache[b][s<512][h][d] (dual) -> Vt[bh][d][s] bf16 (transposed)
// grid = 64 bh * 8 stiles * 2 dtiles = 1024
// ---------------------------------------------------------------------------
__global__ __launch_bounds__(256) void k_cache_v(const bf16* __restrict__ vcb,
                                                 const float* __restrict__ vcf,
                                                 bf16* __restrict__ Vt,
                                                 const int* __restrict__ flag) {
    __shared__ uint32_t T[64][36];
    int f32 = *flag;
    int bid = blockIdx.x;
    int dt = bid & 1, st = (bid >> 1) & 7, bh = bid >> 4;
    int b = bh >> 4, h = bh & 15;
    int t = threadIdx.x, rp = t >> 3, nc = t & 7;
    int s0 = st * 64 + 2 * rp;
    size_t off0 = ((size_t)(b * 2048 + s0) * 16 + h) * Dh + dt * 64 + nc * 8;
    size_t off1 = ((size_t)(b * 2048 + s0 + 1) * 16 + h) * Dh + dt * 64 + nc * 8;
    uint32_t av[4], bv[4];
    if (f32) {
        float4 a0 = *(const float4*)(vcf + off0), a1 = *(const float4*)(vcf + off0 + 4);
        float4 b0 = *(const float4*)(vcf + off1), b1 = *(const float4*)(vcf + off1 + 4);
        av[0]=pack2(a0.x,a0.y); av[1]=pack2(a0.z,a0.w); av[2]=pack2(a1.x,a1.y); av[3]=pack2(a1.z,a1.w);
        bv[0]=pack2(b0.x,b0.y); bv[1]=pack2(b0.z,b0.w); bv[2]=pack2(b1.x,b1.y); bv[3]=pack2(b1.z,b1.w);
    } else {
        uint4 a = *(const uint4*)(vcb + off0);
        uint4 bq = *(const uint4*)(vcb + off1);
        av[0]=a.x; av[1]=a.y; av[2]=a.z; av[3]=a.w;
        bv[0]=bq.x; bv[1]=bq.y; bv[2]=bq.z; bv[3]=bq.w;
    }
#pragma unroll
    for (int i = 0; i < 4; i++) {
        T[nc * 8 + 2 * i    ][rp] = (av[i] & 0xffffu) | (bv[i] << 16);
        T[nc * 8 + 2 * i + 1][rp] = (av[i] >> 16) | (bv[i] & 0xffff0000u);
    }
    __syncthreads();
#pragma unroll
    for (int st2 = 0; st2 < 2; ++st2) {
        int s2 = t + st2 * 256;
        int n = s2 & 63, c4 = s2 >> 6;
        uint4 o;
        o.x = T[n][c4 * 4]; o.y = T[n][c4 * 4 + 1]; o.z = T[n][c4 * 4 + 2]; o.w = T[n][c4 * 4 + 3];
        *(uint4*)(Vt + ((size_t)bh * Dh + dt * 64 + n) * Stot + st * 64 + c4 * 8) = o;
    }
}

// ---------------------------------------------------------------------------
// QKV GEMM with routed epilogue: qkv = x_ln * Wt^T + attn_b, split directly:
//   cols [0,2048)    -> Qb[token][2048]            (bf16)
//   cols [2048,4096) -> Kt[bh][512+s][d]           (bf16)
//   cols [4096,6144) -> Vt[bh][d][512+s]           (bf16, transposed via quad)
// m97-style global_load_lds staging, 128x128 tile, BK=64.
// ---------------------------------------------------------------------------
__global__ __launch_bounds__(256) void k_gemm_qkv(const bf16* __restrict__ A,
                                                  const bf16* __restrict__ Bt,
                                                  const bf16* __restrict__ biasb,
                                                  const float* __restrict__ biasf,
                                                  bf16* __restrict__ Qb,
                                                  bf16* __restrict__ Kt,
                                                  bf16* __restrict__ Vt,
                                                  const int* __restrict__ flag) {
    __shared__ char smem[32768];
    constexpr int K = 2048;
    int f32 = *flag;
    int bm = blockIdx.x & 31, bn = blockIdx.x >> 5;   // M=4096 -> 32 m-tiles
    int tid = threadIdx.x, lane = tid & 63, quad = lane >> 4, l15 = lane & 15;
    int w = tid >> 6, wm = w >> 1, wn = w & 1;
    f32x4 acc[4][4] = {};
    const bf16* Abase = A  + (size_t)(bm * 128) * K;
    const bf16* Bbase = Bt + (size_t)(bn * 128) * K;

    for (int kt = 0; kt < K; kt += 64) {
        __syncthreads();
#pragma unroll
        for (int stp = 0; stp < 4; ++stp) {
            int sbase = stp * 256 + w * 64;
            int s = sbase + lane;
            int row = s >> 3, cc = s & 7, gc = cc ^ (row & 7);
            gload_lds16(Abase + (size_t)row * K + kt + gc * 8, smem + sbase * 16);
            gload_lds16(Bbase + (size_t)row * K + kt + gc * 8, smem + 16384 + sbase * 16);
        }
        __syncthreads();
#pragma unroll
        for (int kk = 0; kk < 2; ++kk) {
            bfx8 af[4], bfr[4];
#pragma unroll
            for (int i = 0; i < 4; i++) {
                int row = wm * 64 + i * 16 + l15;
                int ch = (kk * 4 + quad) ^ (row & 7);
                af[i] = *(const bfx8*)(smem + row * 128 + ch * 16);
            }
#pragma unroll
            for (int j = 0; j < 4; j++) {
                int row = wn * 64 + j * 16 + l15;
                int ch = (kk * 4 + quad) ^ (row & 7);
                bfr[j] = *(const bfx8*)(smem + 16384 + row * 128 + ch * 16);
            }
#pragma unroll
            for (int i = 0; i < 4; i++)
#pragma unroll
                for (int j = 0; j < 4; j++)
                    acc[i][j] = MFMA(af[i], bfr[j], acc[i][j], 0, 0, 0);
        }
    }
    float bsv[4];
#pragma unroll
    for (int j = 0; j < 4; j++) {
        int col = bn * 128 + wn * 64 + j * 16 + l15;
        bsv[j] = f32 ? biasf[col] : (float)biasb[col];
    }
#pragma unroll
    for (int i = 0; i < 4; i++) {
        int m0 = bm * 128 + wm * 64 + i * 16 + quad * 4;   // token of r=0 (4-aligned)
        int b = m0 >> 10, s = m0 & 1023;
#pragma unroll
        for (int j = 0; j < 4; j++) {
            int col = bn * 128 + wn * 64 + j * 16 + l15;
            float v0 = acc[i][j][0] + bsv[j], v1 = acc[i][j][1] + bsv[j];
            float v2 = acc[i][j][2] + bsv[j], v3 = acc[i][j][3] + bsv[j];
            if (col < 2048) {
                bf16* p = Qb + (size_t)m0 * 2048 + col;
                p[0] = (bf16)v0; p[2048] = (bf16)v1; p[4096] = (bf16)v2; p[6144] = (bf16)v3;
            } else if (col < 4096) {
                int hd = col - 2048, h = hd >> 7, d = hd & 127;
                bf16* p = Kt + ((size_t)((b << 4) + h) * Stot + Ccache + s) * Dh + d;
                p[0] = (bf16)v0; p[128] = (bf16)v1; p[256] = (bf16)v2; p[384] = (bf16)v3;
            } else {
                int hd = col - 4096, h = hd >> 7, d = hd & 127;
                bfx4 pv = {(bf16)v0, (bf16)v1, (bf16)v2, (bf16)v3};
                *(bfx4*)(Vt + ((size_t)((b << 4) + h) * Dh + d) * Stot + Ccache + s) = pv;
            }
        }
    }
}

// ---------------------------------------------------------------------------
// Plain GEMM: C = A[M,K]*Bt[N,K]^T + bias (for c_proj). global_load_lds staging.
// ---------------------------------------------------------------------------
__global__ __launch_bounds__(256) void k_gemm_bt(const bf16* __restrict__ A,
                                                 const bf16* __restrict__ Bt,
                                                 const bf16* __restrict__ biasb,
                                                 const float* __restrict__ biasf,
                                                 void* __restrict__ Cout,
                                                 int M, int N, int K,
                                                 const int* __restrict__ flag,
                                                 int want_f32_out) {
    __shared__ char smem[32768];
    int f32 = *flag;
    int f32o = want_f32_out & f32;
    int nbm = M >> 7;
    int bm = blockIdx.x % nbm, bn = blockIdx.x / nbm;
    int tid = threadIdx.x, lane = tid & 63, quad = lane >> 4, l15 = lane & 15;
    int w = tid >> 6, wm = w >> 1, wn = w & 1;
    f32x4 acc[4][4] = {};
    const bf16* Abase = A  + (size_t)(bm * 128) * K;
    const bf16* Bbase = Bt + (size_t)(bn * 128) * K;

    for (int kt = 0; kt < K; kt += 64) {
        __syncthreads();
#pragma unroll
        for (int stp = 0; stp < 4; ++stp) {
            int sbase = stp * 256 + w * 64;
            int s = sbase + lane;
            int row = s >> 3, cc = s & 7, gc = cc ^ (row & 7);
            gload_lds16(Abase + (size_t)row * K + kt + gc * 8, smem + sbase * 16);
            gload_lds16(Bbase + (size_t)row * K + kt + gc * 8, smem + 16384 + sbase * 16);
        }
        __syncthreads();
#pragma unroll
        for (int kk = 0; kk < 2; ++kk) {
            bfx8 af[4], bfr[4];
#pragma unroll
            for (int i = 0; i < 4; i++) {
                int row = wm * 64 + i * 16 + l15;
                int ch = (kk * 4 + quad) ^ (row & 7);
                af[i] = *(const bfx8*)(smem + row * 128 + ch * 16);
            }
#pragma unroll
            for (int j = 0; j < 4; j++) {
                int row = wn * 64 + j * 16 + l15;
                int ch = (kk * 4 + quad) ^ (row & 7);
                bfr[j] = *(const bfx8*)(smem + 16384 + row * 128 + ch * 16);
            }
#pragma unroll
            for (int i = 0; i < 4; i++)
#pragma unroll
                for (int j = 0; j < 4; j++)
                    acc[i][j] = MFMA(af[i], bfr[j], acc[i][j], 0, 0, 0);
        }
    }
    float bsv[4];
#pragma unroll
    for (int j = 0; j < 4; j++) {
        int idx = bn * 128 + wn * 64 + j * 16 + l15;
        bsv[j] = f32 ? biasf[idx] : (float)biasb[idx];
    }
    bf16*  Cb = (bf16*)Cout;
    float* Cf = (float*)Cout;
#pragma unroll
    for (int i = 0; i < 4; i++) {
        int mrow = bm * 128 + wm * 64 + i * 16 + quad * 4;
#pragma unroll
        for (int j = 0; j < 4; j++) {
            int ncol = bn * 128 + wn * 64 + j * 16 + l15;
#pragma unroll
            for (int r = 0; r < 4; r++) {
                float val = acc[i][j][r] + bsv[j];
                if (f32o) Cf[(size_t)(mrow + r) * N + ncol] = val;
                else      Cb[(size_t)(mrow + r) * N + ncol] = (bf16)val;
            }
        }
    }
}

// ---------------------------------------------------------------------------
// Flash attention: S^T = K*Q^T ; O^T = V^T * P^T.  All-bf16 inputs:
//   Qb[token][2048], Kt[bh][s][d], Vt[bh][d][s].  global_load_lds staging,
//   2 barriers per k-tile; per-wave P relayout (lgkm-only wait).
// ---------------------------------------------------------------------------
__global__ __launch_bounds__(256) void k_attn(const bf16* __restrict__ Qb,
                                              const bf16* __restrict__ Kt,
                                              const bf16* __restrict__ Vt,
                                              bf16* __restrict__ aout) {
    __shared__ char smem[51200];  // [0,16K)=K (Q-lo), [16K,32K)=V (Q-hi), [32K,50K)=P
    int bid = blockIdx.x;
    int bh = bid & 63;
    int qi = 7 - (bid >> 6);      // heavy blocks first
    int b = bh >> 4, h = bh & 15;
    int q0 = qi * 128;
    int tid = threadIdx.x, lane = tid & 63, w = tid >> 6, quad = lane >> 4, l15 = lane & 15;

    // stage Q tile [128 q][128 d] (16 chunks/row, XOR-8 swizzle)
#pragma unroll
    for (int stp = 0; stp < 8; ++stp) {
        int sbase = stp * 256 + w * 64, s = sbase + lane;
        int row = s >> 4, cc = s & 15, gc = cc ^ (row & 7);
        gload_lds16(Qb + (size_t)(b * Lq + q0 + row) * 2048 + h * Dh + gc * 8, smem + sbase * 16);
    }
    __syncthreads();
    bfx8 qf[2][4];   // B-operand frags: lane&15 = q, quad = d-chunk
#pragma unroll
    for (int qn = 0; qn < 2; qn++)
#pragma unroll
        for (int c = 0; c < 4; c++) {
            int row = w * 32 + qn * 16 + l15;
            int ch = (c * 4 + quad) ^ (row & 7);
            qf[qn][c] = *(const bfx8*)(smem + row * 256 + ch * 16);
        }
    __syncthreads();   // Q reads done before K staging overwrites

    f32x4 oacc[8][2] = {};
    float mrun[2] = {NEGM, NEGM};
    float lrun[2] = {0.f, 0.f};
    char* Ks = smem;                     // [64 kpos][256B]
    char* Vs = smem + 16384;             // [128 d][128B]
    char* Pw = smem + 32768 + w * 4608;  // per-wave P: [32 q][144B]
    const bf16* Kbh = Kt + (size_t)bh * Stot * Dh;
    const bf16* Vbh = Vt + (size_t)bh * Dh * Stot;

    int nkt = (Ccache + q0 + 128) >> 6;
    for (int kt = 0; kt < nkt; ++kt) {
        int kbase = kt * 64;
#pragma unroll
        for (int stp = 0; stp < 4; ++stp) {   // K tile [64 kpos][128 d]
            int sbase = stp * 256 + w * 64, s = sbase + lane;
            int row = s >> 4, cc = s & 15, gc = cc ^ (row & 7);
            gload_lds16(Kbh + (size_t)(kbase + row) * Dh + gc * 8, Ks + sbase * 16);
        }
#pragma unroll
        for (int stp = 0; stp < 4; ++stp) {   // V^T tile [128 d][64 s]
            int sbase = stp * 256 + w * 64, s = sbase + lane;
            int row = s >> 3, cc = s & 7, gc = cc ^ (row & 7);
            gload_lds16(Vbh + (size_t)row * Stot + kbase + gc * 8, Vs + sbase * 16);
        }
        __syncthreads();   // drain global_load_lds

        // S^T: D[m=kpos][n=q]
        f32x4 sc[4][2] = {};
#pragma unroll
        for (int c = 0; c < 4; c++) {
            bfx8 kf[4];
#pragma unroll
            for (int km = 0; km < 4; km++) {
                int row = km * 16 + l15;
                int ch = (c * 4 + quad) ^ (row & 7);
                kf[km] = *(const bfx8*)(Ks + row * 256 + ch * 16);
            }
#pragma unroll
            for (int km = 0; km < 4; km++)
#pragma unroll
                for (int qn = 0; qn < 2; qn++)
                    sc[km][qn] = MFMA(kf[km], qf[qn][c], sc[km][qn], 0, 0, 0);
        }

        // online softmax; lane holds kpos=km*16+quad*4+r for q=qn*16+l15
        bool domask = (kbase + 63) > (Ccache + q0 + w * 32);
#pragma unroll
        for (int qn = 0; qn < 2; qn++) {
            int qpos = Ccache + q0 + w * 32 + qn * 16 + l15;
            float tv[4][4];
            float tmax = NEGM;
#pragma unroll
            for (int km = 0; km < 4; km++)
#pragma unroll
                for (int r = 0; r < 4; r++) {
                    float vv = sc[km][qn][r] * SCALE_LOG2E;
                    if (domask) {
                        int kp = kbase + km * 16 + quad * 4 + r;
                        vv = (kp <= qpos) ? vv : NEGM;
                    }
                    tv[km][r] = vv;
                    tmax = fmaxf(tmax, vv);
                }
            tmax = fmaxf(tmax, __shfl_xor(tmax, 16));
            tmax = fmaxf(tmax, __shfl_xor(tmax, 32));
            float mnew  = fmaxf(mrun[qn], tmax);
            float alpha = __builtin_amdgcn_exp2f(mrun[qn] - mnew);
            mrun[qn] = mnew;
            float rs = 0.f;
#pragma unroll
            for (int km = 0; km < 4; km++) {
                float a0 = __builtin_amdgcn_exp2f(tv[km][0] - mnew);
                float a1 = __builtin_amdgcn_exp2f(tv[km][1] - mnew);
                float a2 = __builtin_amdgcn_exp2f(tv[km][2] - mnew);
                float a3 = __builtin_amdgcn_exp2f(tv[km][3] - mnew);
                rs += a0 + a1 + a2 + a3;
                bfx4 p = {(bf16)a0, (bf16)a1, (bf16)a2, (bf16)a3};
                *(bfx4*)(Pw + (qn * 16 + l15) * 144 + km * 32 + quad * 8) = p;
            }
            rs += __shfl_xor(rs, 16);
            rs += __shfl_xor(rs, 32);
            lrun[qn] = lrun[qn] * alpha + rs;
#pragma unroll
            for (int dm = 0; dm < 8; dm++)
                oacc[dm][qn] *= alpha;
        }
        asm volatile("s_waitcnt lgkmcnt(0)" ::: "memory");  // wave-private P visible

        // O^T += V^T * P^T
#pragma unroll
        for (int kh = 0; kh < 2; kh++) {
            bfx8 pf[2];
#pragma unroll
            for (int qn = 0; qn < 2; qn++)
                pf[qn] = *(const bfx8*)(Pw + (qn * 16 + l15) * 144 + kh * 64 + quad * 16);
#pragma unroll
            for (int dm = 0; dm < 8; dm++) {
                int row = dm * 16 + l15;
                int ch = (kh * 4 + quad) ^ (row & 7);
                bfx8 vf = *(const bfx8*)(Vs + row * 128 + ch * 16);
#pragma unroll
                for (int qn = 0; qn < 2; qn++)
                    oacc[dm][qn] = MFMA(vf, pf[qn], oacc[dm][qn], 0, 0, 0);
            }
        }
        __syncthreads();   // K/V LDS free for next staging
    }

    // epilogue: O[q][d] = oacc[d][q] / l
#pragma unroll
    for (int qn = 0; qn < 2; qn++) {
        float rl = 1.f / lrun[qn];
        int trow = b * Lq + q0 + w * 32 + qn * 16 + l15;
#pragma unroll
        for (int dm = 0; dm < 8; dm++) {
            bfx4 o = {(bf16)(oacc[dm][qn][0] * rl), (bf16)(oacc[dm][qn][1] * rl),
                      (bf16)(oacc[dm][qn][2] * rl), (bf16)(oacc[dm][qn][3] * rl)};
            *(bfx4*)(aout + (size_t)trow * Hdim + h * Dh + dm * 16 + quad * 4) = o;
        }
    }
}

// ---------------------------------------------------------------------------
extern "C" void kernel_launch(void* const* d_in, const int* in_sizes, int n_in,
                              void* d_out, int out_size, void* d_ws, size_t ws_size,
                              hipStream_t stream) {
    char* ws = (char*)d_ws;
    // ws layout (peak 88 MiB + 4 B, proven watermark):
    bf16* x_ln = (bf16*)(ws);                      // [0,16M)  dead after QKV GEMM
    bf16* Wt   = (bf16*)(ws + (16u << 20));        // [16M,40M) dead after QKV GEMM
    bf16* Kt   = (bf16*)(ws + (40u << 20));        // [40M,64M) [bh][1536][128]
    bf16* Vt   = (bf16*)(ws + (64u << 20));        // [64M,88M) [bh][128][1536]
    int*  flag = (int*)(ws + (88u << 20));         // 4 B
    bf16* Pt   = (bf16*)(ws);                      // [0,8M)   after QKV GEMM
    bf16* aout = (bf16*)(ws + (16u << 20));        // [16M,32M) after QKV GEMM
    bf16* Qb   = (bf16*)d_out;                     // 16M scratch inside 32M d_out

    k_detect<<<dim3(1), dim3(256), 0, stream>>>((const uint32_t*)d_in[0], flag);
    k_ln<<<dim3(4096), dim3(256), 0, stream>>>(
        (const bf16*)d_in[0], (const float*)d_in[0],
        (const bf16*)d_in[6], (const float*)d_in[6],
        (const bf16*)d_in[7], (const float*)d_in[7], x_ln, flag);
    k_transpose<<<dim3(32 * 96), dim3(256), 0, stream>>>(
        (const bf16*)d_in[8], (const float*)d_in[8], Wt, 2048, 6144, flag);
    k_cache_k<<<dim3(2048), dim3(256), 0, stream>>>(
        (const bf16*)d_in[2], (const float*)d_in[2], Kt, flag);
    k_cache_v<<<dim3(1024), dim3(256), 0, stream>>>(
        (const bf16*)d_in[3], (const float*)d_in[3], Vt, flag);
    k_gemm_qkv<<<dim3(32 * 48), dim3(256), 0, stream>>>(
        x_ln, Wt, (const bf16*)d_in[9], (const float*)d_in[9], Qb, Kt, Vt, flag);
    k_transpose<<<dim3(32 * 32), dim3(256), 0, stream>>>(
        (const bf16*)d_in[10], (const float*)d_in[10], Pt, 2048, 2048, flag);
    k_attn<<<dim3(512), dim3(256), 0, stream>>>(Qb, Kt, Vt, aout);
    k_gemm_bt<<<dim3(16 * 32), dim3(256), 0, stream>>>(
        aout, Pt, (const bf16*)d_in[11], (const float*)d_in[11],
        d_out, 4096, 2048, 2048, flag, 1);
}